// Round 6
// baseline (1500.320 us; speedup 1.0000x reference)
//
#include <hip/hip_runtime.h>
#include <hip/hip_bf16.h>
#include <stdint.h>

typedef __attribute__((ext_vector_type(8))) __bf16 bf16x8;
typedef __attribute__((ext_vector_type(8))) short short8;
typedef __attribute__((ext_vector_type(4))) float floatx4;
using bf16 = __hip_bfloat16;

#define DEVINL __device__ __forceinline__

typedef __attribute__((address_space(1))) const void gconst_void;
typedef __attribute__((address_space(3))) void lds_void;

DEVINL void gl2lds16(const void* g, void* l) {
    __builtin_amdgcn_global_load_lds((gconst_void*)g, (lds_void*)l, 16, 0, 0);
}

DEVINL unsigned short f2us(float x) {
    bf16 h = __float2bfloat16(x);
    return __builtin_bit_cast(unsigned short, h);
}
// flag==1: inputs are f32; flag==0: inputs are bf16
DEVINL float ld_in(const void* p, int f, size_t i) {
    return f ? ((const float*)p)[i] : __bfloat162float(((const bf16*)p)[i]);
}

// ---------------- dtype probe (confirmed: inputs are f32; keep hedge) ----------------
__global__ void detect_k(const void* x, int* flag) {
    if (threadIdx.x == 0) {
        const float* xf = (const float*)x;
        int good = 0;
        for (int i = 0; i < 64; i++) {
            float a = fabsf(xf[i]);
            if (a > 1e-8f && a < 100.f) good++;
        }
        *flag = (good >= 48) ? 1 : 0;
    }
}

// ---------------- prep kernels ----------------

__global__ void zero_border_k(bf16* buf, int C) {
    int cell = blockIdx.x;   // 0..259
    int b = blockIdx.y;
    int hp, wp;
    if (cell < 66)       { hp = 0;          wp = cell; }
    else if (cell < 132) { hp = 65;         wp = cell - 66; }
    else if (cell < 196) { hp = cell - 131; wp = 0; }
    else                 { hp = cell - 195; wp = 65; }
    unsigned short* p = (unsigned short*)buf + (size_t)(b * 4356 + hp * 66 + wp) * C;
    for (int c = threadIdx.x; c < C; c += 256) p[c] = 0;
}

// zero pad channels 1632..1663 of Xb for every cell (keeps MFMA inputs clean; weights there are 0)
__global__ void zero_chanpad_k(bf16* Xb, int n) {   // n = G*4356*4
    int idx = blockIdx.x * 256 + threadIdx.x;
    if (idx >= n) return;
    int cell = idx >> 2, sub = idx & 3;
    uint4 z; z.x = 0; z.y = 0; z.z = 0; z.w = 0;
    *(uint4*)((unsigned short*)Xb + (size_t)cell * 1664 + 1632 + sub * 8) = z;
}

__global__ void nchw_to_pnhwc_k(const void* __restrict__ src, bf16* __restrict__ dst,
                                const int* __restrict__ flag,
                                int Csrc, int dstC, int chanOff, int b0) {
    __shared__ unsigned short t[32][72];
    int c0 = blockIdx.x * 32, h = blockIdx.y, bz = blockIdx.z;
    int tid = threadIdx.x;
    {
        int c = tid >> 3, w8 = (tid & 7) * 8;
        size_t base = (((size_t)((b0 + bz) * Csrc + c0 + c)) * 64 + h) * 64 + w8;
        unsigned short* tp = &t[c][w8];
        if (*flag) {
            const float* sf = (const float*)src;
            float4 v0 = *(const float4*)(sf + base);
            float4 v1 = *(const float4*)(sf + base + 4);
            tp[0] = f2us(v0.x); tp[1] = f2us(v0.y); tp[2] = f2us(v0.z); tp[3] = f2us(v0.w);
            tp[4] = f2us(v1.x); tp[5] = f2us(v1.y); tp[6] = f2us(v1.z); tp[7] = f2us(v1.w);
        } else {
            uint4 v = *(const uint4*)((const unsigned short*)src + base);
            *(uint4*)tp = v;
        }
    }
    __syncthreads();
    {
        int w = tid >> 2, cq = (tid & 3) * 8;
        uint32_t p0 = t[cq + 0][w] | ((uint32_t)t[cq + 1][w] << 16);
        uint32_t p1 = t[cq + 2][w] | ((uint32_t)t[cq + 3][w] << 16);
        uint32_t p2 = t[cq + 4][w] | ((uint32_t)t[cq + 5][w] << 16);
        uint32_t p3 = t[cq + 6][w] | ((uint32_t)t[cq + 7][w] << 16);
        uint4 o; o.x = p0; o.y = p1; o.z = p2; o.w = p3;
        size_t off = ((size_t)(bz * 4356 + (h + 1) * 66 + (w + 1))) * dstC + chanOff + c0 + cq;
        *(uint4*)((unsigned short*)dst + off) = o;
    }
}

__global__ void raw_patches_k(const void* __restrict__ raw, bf16* __restrict__ Xa,
                              const int* __restrict__ flag, int b0) {
    __shared__ unsigned short t[8][520];
    int h = blockIdx.x, craw = blockIdx.y, bz = blockIdx.z;
    int tid = threadIdx.x;
    int f = *flag;
#pragma unroll
    for (int k = 0; k < 2; k++) {
        int s = tid + k * 256;
        int gy = s >> 6, seg = s & 63;
        size_t base = (((size_t)((b0 + bz) * 3 + craw) * 512) + gy * 64 + h) * 512 + seg * 8;
        unsigned short* tp = &t[gy][seg * 8];
        if (f) {
            const float* rf = (const float*)raw;
            float4 v0 = *(const float4*)(rf + base);
            float4 v1 = *(const float4*)(rf + base + 4);
            tp[0] = f2us(v0.x); tp[1] = f2us(v0.y); tp[2] = f2us(v0.z); tp[3] = f2us(v0.w);
            tp[4] = f2us(v1.x); tp[5] = f2us(v1.y); tp[6] = f2us(v1.z); tp[7] = f2us(v1.w);
        } else {
            uint4 v = *(const uint4*)((const unsigned short*)raw + base);
            *(uint4*)tp = v;
        }
    }
    __syncthreads();
#pragma unroll
    for (int k = 0; k < 2; k++) {
        int s = tid + k * 256;
        int w = s >> 3, gq = s & 7;
        uint32_t p0 = t[gq][0 * 64 + w] | ((uint32_t)t[gq][1 * 64 + w] << 16);
        uint32_t p1 = t[gq][2 * 64 + w] | ((uint32_t)t[gq][3 * 64 + w] << 16);
        uint32_t p2 = t[gq][4 * 64 + w] | ((uint32_t)t[gq][5 * 64 + w] << 16);
        uint32_t p3 = t[gq][6 * 64 + w] | ((uint32_t)t[gq][7 * 64 + w] << 16);
        uint4 o; o.x = p0; o.y = p1; o.z = p2; o.w = p3;
        size_t off = ((size_t)(bz * 4356 + (h + 1) * 66 + (w + 1))) * 576 + 384 + craw * 64 + gq * 8;
        *(uint4*)((unsigned short*)Xa + off) = o;
    }
}

// srcC = real input channels of the torch weight; dstC = padded K-stride of folded buffer.
// Output rows padded to 640 (rows 576..639 zero) -> 2 exact BN=320 tiles.
__global__ void fold_w_k(const void* __restrict__ W, bf16* __restrict__ dst,
                         const int* __restrict__ flag, int srcC, int dstC, int remap) {
    int ci = blockIdx.x * 256 + threadIdx.x;
    if (ci >= dstC) return;
    int co = blockIdx.y;  // 0..639
    int kk = blockIdx.z;  // 0..8
    unsigned short out = 0;
    if (co < 576 && ci < srcC) {
        int oc = ci;
        if (remap && ci >= 384) {
            int tt = ci - 384;
            int craw = tt >> 6, gy = (tt >> 3) & 7, gx = tt & 7;
            oc = 384 + gy * 24 + gx * 3 + craw;
        }
        size_t sidx = ((size_t)co * srcC + oc) * 9 + kk;
        out = (*flag) ? f2us(((const float*)W)[sidx]) : ((const unsigned short*)W)[sidx];
    }
    ((unsigned short*)dst)[((size_t)kk * 640 + co) * dstC + ci] = out;
}

__global__ void scale_beta_k(const void* g, const void* b, const void* m, const void* v,
                             const int* __restrict__ flag, float* inv_out, float* beta_out) {
    int i = blockIdx.x * 256 + threadIdx.x;
    int f = *flag;
    if (i < 576) {
        float inv = ld_in(g, f, i) / sqrtf(ld_in(v, f, i) + 1e-5f);
        inv_out[i] = inv;
        beta_out[i] = ld_in(b, f, i) - ld_in(m, f, i) * inv;
    }
}

// ---------------- 3x3 conv, implicit GEMM, 1-barrier pipeline + wave kq-stagger ----------------
// BM=256 BN=320 BK=64, 512 thr / 8 waves (2M x 4N, wave tile 128x80, acc 8x5).
// r6 changes vs r5 (both de-serialize the tile body):
//  (1) ONE barrier per K-tile: the validity barrier {vmcnt(0); s_barrier} at tile
//      top also proves every wave finished tile t-1's body (reads of buf p^1),
//      so issuing ALL 9 stage loads AFTER it makes r5's end-of-tile barrier
//      redundant. The 9 outstanding loads at the wait are all tile-t's, issued a
//      full tile (~5000 cyc) earlier >> 900 cyc HBM latency -> wait is ~free.
//  (2) kq-stagger: waves with key=(wv^(wv>>2))&1 process kq1 before kq0
//      (K-accumulation commutes; both halves staged before the barrier). Key
//      differs within a SIMD wave-pair under either i%4 or i/2 assignment, so
//      each SIMD's 2 waves are in opposite read/MFMA phases -> LDS reads co-run
//      with MFMA instead of alternating (r5: read demand 2496 cyc ~= MFMA floor
//      3104 cyc/K-tile, so overlap is mandatory to approach the floor).
// T2 XOR swizzle both-sides (0 conflicts, r1-r5). T5 setprio. T1 XCD swizzle.
__global__ __launch_bounds__(512, 2)
void conv3x3_mfma(const bf16* __restrict__ X, const bf16* __restrict__ Wp,
                  const float* __restrict__ inv, const float* __restrict__ beta,
                  bf16* __restrict__ dst, int Cin, int dstC, int chanOff, int dstPadded,
                  int mtiles) {
    __shared__ __align__(16) bf16 Alds[2 * 16384];   // 2 x 32 KB : [256 rows][64]
    __shared__ __align__(16) bf16 Blds[2 * 20480];   // 2 x 40 KB : [320 rows][64]
    const int tid = threadIdx.x;
    const int wv = tid >> 6;
    const int lane = tid & 63;
    const int quad = lane >> 4;
    const int r16 = lane & 15;

    // T1: XCD-contiguous remap (nwg = 32*G, always % 8 == 0)
    const int nwg = gridDim.x;
    const int wg = ((int)blockIdx.x & 7) * (nwg >> 3) + ((int)blockIdx.x >> 3);
    const int m0 = (wg % mtiles) * 256;
    const int n0 = (wg / mtiles) * 320;

    // staging: each 64-row chunk = 8 KB = one gl2lds across 512 threads
    const int rl = tid >> 3;                          // 0..63 (row within chunk)
    const int cg = ((tid & 7) ^ (rl & 7)) * 8;        // inverse-swizzled source chunk (halfwords)
    int aF[4], bF[5];
#pragma unroll
    for (int q = 0; q < 4; q++) {
        int r = m0 + q * 64 + rl;
        int bb = r >> 12, hh = (r >> 6) & 63;
        aF[q] = (bb * 4356 + (hh + 1) * 66 + (rl + 1)) * Cin + cg;
    }
#pragma unroll
    for (int q = 0; q < 5; q++) bF[q] = (n0 + q * 64 + rl) * Cin + cg;

    // fragment-read geometry (wave tile 128x80: 8 M-frags x 5 N-frags)
    const int wvM = wv >> 2, wvN = wv & 3;
    int aOff[8], bOff[5];
#pragma unroll
    for (int i = 0; i < 8; i++) aOff[i] = (wvM * 128 + i * 16 + r16) * 64;
#pragma unroll
    for (int j = 0; j < 5; j++) bOff[j] = (wvN * 80 + j * 16 + r16) * 64;
    const int sw0 = (quad ^ (r16 & 7)) * 8;           // swizzled chunk, kq=0
    const int sw1 = ((quad + 4) ^ (r16 & 7)) * 8;     // swizzled chunk, kq=1
    // kq-stagger: this wave's first/second kq chunk offsets
    const int kqsel = (wv ^ (wv >> 2)) & 1;
    const int sA = kqsel ? sw1 : sw0;
    const int sB = kqsel ? sw0 : sw1;

    floatx4 acc[8][5];
    floatx4 zero = {0.f, 0.f, 0.f, 0.f};
#pragma unroll
    for (int i = 0; i < 8; i++)
#pragma unroll
        for (int j = 0; j < 5; j++) acc[i][j] = zero;

#define BAR() asm volatile("s_barrier" ::: "memory")
#define READB(sw) do { \
    _Pragma("unroll") for (int j_ = 0; j_ < 5; j_++) \
        bfr[j_] = *(const short8*)(Bp + bOff[j_] + (sw)); } while (0)
#define READA(h, sw) do { \
    _Pragma("unroll") for (int i_ = 0; i_ < 4; i_++) \
        af[i_] = *(const short8*)(Ap + aOff[(h) * 4 + i_] + (sw)); } while (0)
#define MM(h) do { \
    __builtin_amdgcn_s_setprio(1); \
    _Pragma("unroll") for (int i_ = 0; i_ < 4; i_++) \
    _Pragma("unroll") for (int j_ = 0; j_ < 5; j_++) \
        acc[(h) * 4 + i_][j_] = __builtin_amdgcn_mfma_f32_16x16x32_bf16( \
            __builtin_bit_cast(bf16x8, af[i_]), __builtin_bit_cast(bf16x8, bfr[j_]), \
            acc[(h) * 4 + i_][j_], 0, 0, 0); \
    __builtin_amdgcn_s_setprio(0); } while (0)
#define GA(q) gl2lds16(X + aF[q] + so, Ao + (q) * 4096 + wv * 512)
#define GB(q) gl2lds16(Wp + bF[q] + wo, Bo + (q) * 4096 + wv * 512)
#define ADV() do { ciN += 64; if (ciN == Cin) { ciN = 0; ++kkN; \
        tapOffN = ((kkN / 3) * 66 + (kkN % 3) - 67) * Cin; wbN += 640 * Cin; } } while (0)

    // flat K bookkeeping: (kkN, ciN) = coordinates of the NEXT tile to stage
    int kkN = 0, ciN = 0, tapOffN = -67 * Cin, wbN = 0;   // tap 0: dh=-1,dw=-1
    {   // prologue: stage tile 0 fully into buf 0
        const int so = tapOffN + ciN, wo = wbN + ciN;
        bf16* Ao = Alds; bf16* Bo = Blds;
        GA(0); GA(1); GA(2); GA(3);
        GB(0); GB(1); GB(2); GB(3); GB(4);
    }
    ADV();
    const int NT = 9 * (Cin >> 6);
    int p = 0;
    for (int t = 0; t < NT - 1; ++t, p ^= 1) {
        const bf16* Ap = Alds + p * 16384;
        const bf16* Bp = Blds + p * 20480;
        bf16* Ao = Alds + (p ^ 1) * 16384;
        bf16* Bo = Blds + (p ^ 1) * 20480;
        const int so = tapOffN + ciN, wo = wbN + ciN;
        short8 af[4], bfr[5];
        // single validity barrier: tile t's 9 loads landed (vmcnt) AND every
        // wave finished tile t-1's body (barrier) -> staging buf p^1 is safe
        asm volatile("s_waitcnt vmcnt(0)" ::: "memory");
        BAR();
        READB(sA); READA(0, sA);
        MM(0);
        GA(0); GA(1); GA(2);
        READA(1, sA);
        MM(1);
        GA(3); GB(0); GB(1);
        READB(sB); READA(0, sB);
        MM(0);
        GB(2); GB(3); GB(4);
        READA(1, sB);
        MM(1);
        ADV();
    }
    {   // last tile: no staging
        const bf16* Ap = Alds + p * 16384;
        const bf16* Bp = Blds + p * 20480;
        short8 af[4], bfr[5];
        asm volatile("s_waitcnt vmcnt(0)" ::: "memory");
        BAR();
        READB(sA); READA(0, sA); MM(0);
        READA(1, sA); MM(1);
        READB(sB); READA(0, sB); MM(0);
        READA(1, sB); MM(1);
    }
#undef BAR
#undef READB
#undef READA
#undef MM
#undef GA
#undef GB
#undef ADV

    // epilogue (loads kept OUT of the loop so vmcnt counting stays exact):
    // D[row=quad*4+r, col=lane&15] (verified m89/m91 layout)
    int ncol[5]; float sj[5], bj[5]; bool nval[5];
#pragma unroll
    for (int j = 0; j < 5; j++) {
        ncol[j] = n0 + wvN * 80 + j * 16 + r16;
        nval[j] = ncol[j] < 576;
        sj[j] = nval[j] ? inv[ncol[j]] : 0.f;
        bj[j] = nval[j] ? beta[ncol[j]] : 0.f;
    }
#pragma unroll
    for (int i = 0; i < 8; i++) {
#pragma unroll
        for (int r = 0; r < 4; r++) {
            int row = m0 + wvM * 128 + i * 16 + quad * 4 + r;
            int didx;
            if (dstPadded) {
                int bb = row >> 12, hh = (row >> 6) & 63, ww = row & 63;
                didx = (bb * 4356 + (hh + 1) * 66 + (ww + 1)) * dstC + chanOff;
            } else {
                didx = row * dstC + chanOff;
            }
#pragma unroll
            for (int j = 0; j < 5; j++)
                if (nval[j]) dst[didx + ncol[j]] = __float2bfloat16(acc[i][j][r] * sj[j] + bj[j]);
        }
    }
}

// ---------------- tail: 1x1 conv (576->1) + x8 bilinear upsample ----------------
__global__ void o2_dot_k(const bf16* __restrict__ Y, const void* __restrict__ w,
                         const void* __restrict__ bias, const int* __restrict__ flag,
                         float* __restrict__ smap) {
    __shared__ float wl[576];
    int tid = threadIdx.x;
    int f = *flag;
    for (int c = tid; c < 576; c += 256) wl[c] = ld_in(w, f, c);
    __syncthreads();
    int wv = tid >> 6, lane = tid & 63;
    int pix = blockIdx.x * 4 + wv;
    const bf16* yp = Y + (size_t)pix * 576;
    float s = 0.f;
#pragma unroll
    for (int k = 0; k < 9; k++) {
        int c = k * 64 + lane;
        s += __bfloat162float(yp[c]) * wl[c];
    }
#pragma unroll
    for (int off = 32; off; off >>= 1) s += __shfl_xor(s, off, 64);
    if (lane == 0) smap[pix] = s + ld_in(bias, f, 0);
}

__global__ void upsample_k(const float* __restrict__ smap, void* __restrict__ out,
                           const int* __restrict__ flag) {
    int idx = blockIdx.x * 256 + threadIdx.x;   // 8*512*512 exact
    int b = idx >> 18;
    int ho = (idx >> 9) & 511;
    int wo = idx & 511;
    const float sc = 63.f / 511.f;              // align_corners=True
    float ys = ho * sc, xs = wo * sc;
    int y0 = (int)ys; float ty = ys - y0; int y1 = min(y0 + 1, 63);
    int x0 = (int)xs; float tx = xs - x0; int x1 = min(x0 + 1, 63);
    const float* sp = smap + (b << 12);
    float r0 = sp[y0 * 64 + x0] * (1.f - tx) + sp[y0 * 64 + x1] * tx;
    float r1 = sp[y1 * 64 + x0] * (1.f - tx) + sp[y1 * 64 + x1] * tx;
    float val = r0 * (1.f - ty) + r1 * ty;
    if (*flag) ((float*)out)[idx] = val;
    else       ((bf16*)out)[idx] = __float2bfloat16(val);
}

// ---------------- launch ----------------
extern "C" void kernel_launch(void* const* d_in, const int* in_sizes, int n_in,
                              void* d_out, int out_size, void* d_ws, size_t ws_size,
                              hipStream_t stream) {
    const void* coarse = d_in[0];
    const void* x22    = d_in[1];
    const void* x31    = d_in[2];
    const void* rawx   = d_in[3];
    // d_in[4]=w_pred, d_in[5]=b_pred : dead code in reference
    const void* dec_w = d_in[6];
    const void *dec_g = d_in[7], *dec_b = d_in[8], *dec_m = d_in[9], *dec_v = d_in[10];
    const void* cc_w = d_in[11];
    const void *cc_g = d_in[12], *cc_b = d_in[13], *cc_m = d_in[14], *cc_v = d_in[15];
    const void* o1_w = d_in[16];
    const void *o1_g = d_in[17], *o1_b = d_in[18], *o1_m = d_in[19], *o1_v = d_in[20];
    const void* o2_w = d_in[21];
    const void* o2_b = d_in[22];

    // adaptive chunk ladder (weights: 640 output rows; cc K-pad 1632->1664)
    const size_t wcc_sz  = (size_t)9 * 640 * 1664 * 2;
    const size_t wsm_sz  = (size_t)9 * 640 * 576 * 2;
    const size_t tail_sz = 16384 + 131072 + 256;
    int G = 8; int sepW = 1;
    for (;;) {
        size_t acts = (size_t)G * 4356 * (576 + 1664) * 2;
        if (acts + wcc_sz + 2 * wsm_sz + tail_sz <= ws_size) { sepW = 1; break; }
        if (acts + wcc_sz + tail_sz <= ws_size)              { sepW = 0; break; }
        if (G == 1) { sepW = 0; break; }
        G >>= 1;
    }
    size_t xa_sz = (size_t)G * 4356 * 576 * 2;
    size_t xb_sz = (size_t)G * 4356 * 1664 * 2;

    char* ws = (char*)d_ws;
    bf16* Xa   = (bf16*)(ws);
    bf16* Xb   = (bf16*)(ws + xa_sz);
    bf16* Wcc  = (bf16*)(ws + xa_sz + xb_sz);
    bf16* Wdec = sepW ? (bf16*)(ws + xa_sz + xb_sz + wcc_sz) : Wcc;
    bf16* Wo1  = sepW ? (bf16*)(ws + xa_sz + xb_sz + wcc_sz + wsm_sz) : Wcc;
    size_t wtot = wcc_sz + (sepW ? 2 * wsm_sz : 0);
    float* sb  = (float*)(ws + xa_sz + xb_sz + wtot);
    float* invDec = sb,        *betaDec = sb + 576;
    float* invCc  = sb + 1152, *betaCc  = sb + 1728;
    float* invO1  = sb + 2304, *betaO1  = sb + 2880;
    float* smap = (float*)(ws + xa_sz + xb_sz + wtot + 16384);
    int* flag   = (int*)(ws + xa_sz + xb_sz + wtot + 16384 + 131072);
    bf16* Yo1q = Xb;

    detect_k<<<1, 64, 0, stream>>>(coarse, flag);
    scale_beta_k<<<3, 256, 0, stream>>>(dec_g, dec_b, dec_m, dec_v, flag, invDec, betaDec);
    scale_beta_k<<<3, 256, 0, stream>>>(cc_g, cc_b, cc_m, cc_v, flag, invCc, betaCc);
    scale_beta_k<<<3, 256, 0, stream>>>(o1_g, o1_b, o1_m, o1_v, flag, invO1, betaO1);
    if (sepW) {
        fold_w_k<<<dim3(3, 640, 9), 256, 0, stream>>>(dec_w, Wdec, flag, 576, 576, 1);
        fold_w_k<<<dim3(7, 640, 9), 256, 0, stream>>>(cc_w, Wcc, flag, 1632, 1664, 0);
        fold_w_k<<<dim3(3, 640, 9), 256, 0, stream>>>(o1_w, Wo1, flag, 576, 576, 0);
    }

    const int nchunk = 8 / G;
    const int mt = G * 16;                 // 256-row M-tiles per chunk
    for (int q = 0; q < nchunk; q++) {
        const int b0 = q * G;
        zero_border_k<<<dim3(260, G), 256, 0, stream>>>(Xa, 576);
        zero_border_k<<<dim3(260, G), 256, 0, stream>>>(Xb, 1664);
        zero_chanpad_k<<<(G * 4356 * 4 + 255) / 256, 256, 0, stream>>>(Xb, G * 4356 * 4);
        nchw_to_pnhwc_k<<<dim3(12, 64, G), 256, 0, stream>>>(coarse, Xa, flag, 384, 576, 0, b0);
        raw_patches_k<<<dim3(64, 3, G), 256, 0, stream>>>(rawx, Xa, flag, b0);
        nchw_to_pnhwc_k<<<dim3(24, 64, G), 256, 0, stream>>>(x22, Xb, flag, 768, 1664, 0, b0);
        nchw_to_pnhwc_k<<<dim3(9, 64, G), 256, 0, stream>>>(x31, Xb, flag, 288, 1664, 1344, b0);
        if (!sepW) fold_w_k<<<dim3(3, 640, 9), 256, 0, stream>>>(dec_w, Wdec, flag, 576, 576, 1);
        conv3x3_mfma<<<dim3(mt * 2), 512, 0, stream>>>(Xa, Wdec, invDec, betaDec, Xb, 576, 1664, 768, 1, mt);
        if (!sepW) fold_w_k<<<dim3(7, 640, 9), 256, 0, stream>>>(cc_w, Wcc, flag, 1632, 1664, 0);
        conv3x3_mfma<<<dim3(mt * 2), 512, 0, stream>>>(Xb, Wcc, invCc, betaCc, Xa, 1664, 576, 0, 1, mt);
        if (!sepW) fold_w_k<<<dim3(3, 640, 9), 256, 0, stream>>>(o1_w, Wo1, flag, 576, 576, 0);
        conv3x3_mfma<<<dim3(mt * 2), 512, 0, stream>>>(Xa, Wo1, invO1, betaO1, Yo1q, 576, 576, 0, 0, mt);
        o2_dot_k<<<G * 1024, 256, 0, stream>>>(Yo1q, o2_w, o2_b, flag, smap + (size_t)q * G * 4096);
    }
    upsample_k<<<8192, 256, 0, stream>>>(smap, d_out, flag);
}

// Round 7
// 1439.614 us; speedup vs baseline: 1.0422x; 1.0422x over previous
//
#include <hip/hip_runtime.h>
#include <hip/hip_bf16.h>
#include <stdint.h>

typedef __attribute__((ext_vector_type(8))) __bf16 bf16x8;
typedef __attribute__((ext_vector_type(8))) short short8;
typedef __attribute__((ext_vector_type(4))) float floatx4;
using bf16 = __hip_bfloat16;

#define DEVINL __device__ __forceinline__

typedef __attribute__((address_space(1))) const void gconst_void;
typedef __attribute__((address_space(3))) void lds_void;

DEVINL void gl2lds16(const void* g, void* l) {
    __builtin_amdgcn_global_load_lds((gconst_void*)g, (lds_void*)l, 16, 0, 0);
}

DEVINL unsigned short f2us(float x) {
    bf16 h = __float2bfloat16(x);
    return __builtin_bit_cast(unsigned short, h);
}
// flag==1: inputs are f32; flag==0: inputs are bf16
DEVINL float ld_in(const void* p, int f, size_t i) {
    return f ? ((const float*)p)[i] : __bfloat162float(((const bf16*)p)[i]);
}

// ---------------- dtype probe (confirmed: inputs are f32; keep hedge) ----------------
__global__ void detect_k(const void* x, int* flag) {
    if (threadIdx.x == 0) {
        const float* xf = (const float*)x;
        int good = 0;
        for (int i = 0; i < 64; i++) {
            float a = fabsf(xf[i]);
            if (a > 1e-8f && a < 100.f) good++;
        }
        *flag = (good >= 48) ? 1 : 0;
    }
}

// ---------------- prep kernels ----------------

__global__ void zero_border_k(bf16* buf, int C) {
    int cell = blockIdx.x;   // 0..259
    int b = blockIdx.y;
    int hp, wp;
    if (cell < 66)       { hp = 0;          wp = cell; }
    else if (cell < 132) { hp = 65;         wp = cell - 66; }
    else if (cell < 196) { hp = cell - 131; wp = 0; }
    else                 { hp = cell - 195; wp = 65; }
    unsigned short* p = (unsigned short*)buf + (size_t)(b * 4356 + hp * 66 + wp) * C;
    for (int c = threadIdx.x; c < C; c += 256) p[c] = 0;
}

// zero pad channels 1632..1663 of Xb for every cell (keeps MFMA inputs clean; weights there are 0)
__global__ void zero_chanpad_k(bf16* Xb, int n) {   // n = G*4356*4
    int idx = blockIdx.x * 256 + threadIdx.x;
    if (idx >= n) return;
    int cell = idx >> 2, sub = idx & 3;
    uint4 z; z.x = 0; z.y = 0; z.z = 0; z.w = 0;
    *(uint4*)((unsigned short*)Xb + (size_t)cell * 1664 + 1632 + sub * 8) = z;
}

__global__ void nchw_to_pnhwc_k(const void* __restrict__ src, bf16* __restrict__ dst,
                                const int* __restrict__ flag,
                                int Csrc, int dstC, int chanOff, int b0) {
    __shared__ unsigned short t[32][72];
    int c0 = blockIdx.x * 32, h = blockIdx.y, bz = blockIdx.z;
    int tid = threadIdx.x;
    {
        int c = tid >> 3, w8 = (tid & 7) * 8;
        size_t base = (((size_t)((b0 + bz) * Csrc + c0 + c)) * 64 + h) * 64 + w8;
        unsigned short* tp = &t[c][w8];
        if (*flag) {
            const float* sf = (const float*)src;
            float4 v0 = *(const float4*)(sf + base);
            float4 v1 = *(const float4*)(sf + base + 4);
            tp[0] = f2us(v0.x); tp[1] = f2us(v0.y); tp[2] = f2us(v0.z); tp[3] = f2us(v0.w);
            tp[4] = f2us(v1.x); tp[5] = f2us(v1.y); tp[6] = f2us(v1.z); tp[7] = f2us(v1.w);
        } else {
            uint4 v = *(const uint4*)((const unsigned short*)src + base);
            *(uint4*)tp = v;
        }
    }
    __syncthreads();
    {
        int w = tid >> 2, cq = (tid & 3) * 8;
        uint32_t p0 = t[cq + 0][w] | ((uint32_t)t[cq + 1][w] << 16);
        uint32_t p1 = t[cq + 2][w] | ((uint32_t)t[cq + 3][w] << 16);
        uint32_t p2 = t[cq + 4][w] | ((uint32_t)t[cq + 5][w] << 16);
        uint32_t p3 = t[cq + 6][w] | ((uint32_t)t[cq + 7][w] << 16);
        uint4 o; o.x = p0; o.y = p1; o.z = p2; o.w = p3;
        size_t off = ((size_t)(bz * 4356 + (h + 1) * 66 + (w + 1))) * dstC + chanOff + c0 + cq;
        *(uint4*)((unsigned short*)dst + off) = o;
    }
}

__global__ void raw_patches_k(const void* __restrict__ raw, bf16* __restrict__ Xa,
                              const int* __restrict__ flag, int b0) {
    __shared__ unsigned short t[8][520];
    int h = blockIdx.x, craw = blockIdx.y, bz = blockIdx.z;
    int tid = threadIdx.x;
    int f = *flag;
#pragma unroll
    for (int k = 0; k < 2; k++) {
        int s = tid + k * 256;
        int gy = s >> 6, seg = s & 63;
        size_t base = (((size_t)((b0 + bz) * 3 + craw) * 512) + gy * 64 + h) * 512 + seg * 8;
        unsigned short* tp = &t[gy][seg * 8];
        if (f) {
            const float* rf = (const float*)raw;
            float4 v0 = *(const float4*)(rf + base);
            float4 v1 = *(const float4*)(rf + base + 4);
            tp[0] = f2us(v0.x); tp[1] = f2us(v0.y); tp[2] = f2us(v0.z); tp[3] = f2us(v0.w);
            tp[4] = f2us(v1.x); tp[5] = f2us(v1.y); tp[6] = f2us(v1.z); tp[7] = f2us(v1.w);
        } else {
            uint4 v = *(const uint4*)((const unsigned short*)raw + base);
            *(uint4*)tp = v;
        }
    }
    __syncthreads();
#pragma unroll
    for (int k = 0; k < 2; k++) {
        int s = tid + k * 256;
        int w = s >> 3, gq = s & 7;
        uint32_t p0 = t[gq][0 * 64 + w] | ((uint32_t)t[gq][1 * 64 + w] << 16);
        uint32_t p1 = t[gq][2 * 64 + w] | ((uint32_t)t[gq][3 * 64 + w] << 16);
        uint32_t p2 = t[gq][4 * 64 + w] | ((uint32_t)t[gq][5 * 64 + w] << 16);
        uint32_t p3 = t[gq][6 * 64 + w] | ((uint32_t)t[gq][7 * 64 + w] << 16);
        uint4 o; o.x = p0; o.y = p1; o.z = p2; o.w = p3;
        size_t off = ((size_t)(bz * 4356 + (h + 1) * 66 + (w + 1))) * 576 + 384 + craw * 64 + gq * 8;
        *(uint4*)((unsigned short*)Xa + off) = o;
    }
}

// srcC = real input channels of the torch weight; dstC = padded K-stride of folded buffer.
// Output rows padded to 640 (rows 576..639 zero) -> 2 exact BN=320 tiles.
__global__ void fold_w_k(const void* __restrict__ W, bf16* __restrict__ dst,
                         const int* __restrict__ flag, int srcC, int dstC, int remap) {
    int ci = blockIdx.x * 256 + threadIdx.x;
    if (ci >= dstC) return;
    int co = blockIdx.y;  // 0..639
    int kk = blockIdx.z;  // 0..8
    unsigned short out = 0;
    if (co < 576 && ci < srcC) {
        int oc = ci;
        if (remap && ci >= 384) {
            int tt = ci - 384;
            int craw = tt >> 6, gy = (tt >> 3) & 7, gx = tt & 7;
            oc = 384 + gy * 24 + gx * 3 + craw;
        }
        size_t sidx = ((size_t)co * srcC + oc) * 9 + kk;
        out = (*flag) ? f2us(((const float*)W)[sidx]) : ((const unsigned short*)W)[sidx];
    }
    ((unsigned short*)dst)[((size_t)kk * 640 + co) * dstC + ci] = out;
}

__global__ void scale_beta_k(const void* g, const void* b, const void* m, const void* v,
                             const int* __restrict__ flag, float* inv_out, float* beta_out) {
    int i = blockIdx.x * 256 + threadIdx.x;
    int f = *flag;
    if (i < 576) {
        float inv = ld_in(g, f, i) / sqrtf(ld_in(v, f, i) + 1e-5f);
        inv_out[i] = inv;
        beta_out[i] = ld_in(b, f, i) - ld_in(m, f, i) * inv;
    }
}

// o2 prep: w2f[0..575] = o2 weights as f32; smap[0..npix-1] = o2 bias (fused o2
// partial-dot results are atomically accumulated on top by the o1 conv epilogue)
__global__ void o2w_k(const void* __restrict__ w, const void* __restrict__ bias,
                      const int* __restrict__ flag, float* __restrict__ w2f,
                      float* __restrict__ smap, int npix) {
    int i = blockIdx.x * 256 + threadIdx.x;
    int f = *flag;
    if (i < 576) w2f[i] = ld_in(w, f, i);
    float b2 = ld_in(bias, f, 0);
    if (i < npix) smap[i] = b2;
}

// ---------------- 3x3 conv, implicit GEMM, 2-barrier double-buffer pipeline ----------------
// BM=256 BN=320 BK=64, 512 thr / 8 waves (2M x 4N, wave tile 128x80, acc 8x5).
// PROVEN r5 schedule (1290us total, MfmaUtil 51%): 2 barriers/K-tile, counted
// vmcnt (never drains in steady state), no intra-tile barriers (compiler
// interleaves ds_reads under MFMA via fine lgkmcnt). r7 deltas vs r5:
//  (1) T4 deepened: 6 of tile t+1's 9 loads issued BEFORE the counted wait
//      (vmcnt(6), m218's operating depth) -- r6 proved drain-to-0 costs ~20%,
//      so more loads in flight across the barrier is the right direction.
//  (2) optional fused o2 epilogue (w2 != nullptr): per-block partial dot
//      (acc*inv+beta).w2 over its 320 cols, butterfly-reduce over the 16-lane
//      col group, atomicAdd into smap (pre-init to b2). Kills the o2_dot
//      dispatch (37.7MB re-read) and o1's 37.7MB dst write.
// T2 XOR swizzle both-sides (0 conflicts, r1-r6). T5 setprio. T1 XCD swizzle.
__global__ __launch_bounds__(512, 2)
void conv3x3_mfma(const bf16* __restrict__ X, const bf16* __restrict__ Wp,
                  const float* __restrict__ inv, const float* __restrict__ beta,
                  bf16* __restrict__ dst, int Cin, int dstC, int chanOff, int dstPadded,
                  int mtiles, const float* __restrict__ w2, float* __restrict__ smap) {
    __shared__ __align__(16) bf16 Alds[2 * 16384];   // 2 x 32 KB : [256 rows][64]
    __shared__ __align__(16) bf16 Blds[2 * 20480];   // 2 x 40 KB : [320 rows][64]
    const int tid = threadIdx.x;
    const int wv = tid >> 6;
    const int lane = tid & 63;
    const int quad = lane >> 4;
    const int r16 = lane & 15;

    // T1: XCD-contiguous remap (nwg = 32*G, always % 8 == 0)
    const int nwg = gridDim.x;
    const int wg = ((int)blockIdx.x & 7) * (nwg >> 3) + ((int)blockIdx.x >> 3);
    const int m0 = (wg % mtiles) * 256;
    const int n0 = (wg / mtiles) * 320;

    // staging: each 64-row chunk = 8 KB = one gl2lds across 512 threads
    const int rl = tid >> 3;                          // 0..63 (row within chunk)
    const int cg = ((tid & 7) ^ (rl & 7)) * 8;        // inverse-swizzled source chunk (halfwords)
    int aF[4], bF[5];
#pragma unroll
    for (int q = 0; q < 4; q++) {
        int r = m0 + q * 64 + rl;
        int bb = r >> 12, hh = (r >> 6) & 63;
        aF[q] = (bb * 4356 + (hh + 1) * 66 + (rl + 1)) * Cin + cg;
    }
#pragma unroll
    for (int q = 0; q < 5; q++) bF[q] = (n0 + q * 64 + rl) * Cin + cg;

    // fragment-read geometry (wave tile 128x80: 8 M-frags x 5 N-frags)
    const int wvM = wv >> 2, wvN = wv & 3;
    int aOff[8], bOff[5];
#pragma unroll
    for (int i = 0; i < 8; i++) aOff[i] = (wvM * 128 + i * 16 + r16) * 64;
#pragma unroll
    for (int j = 0; j < 5; j++) bOff[j] = (wvN * 80 + j * 16 + r16) * 64;
    const int sw0 = (quad ^ (r16 & 7)) * 8;           // swizzled chunk, kq=0
    const int sw1 = ((quad + 4) ^ (r16 & 7)) * 8;     // swizzled chunk, kq=1

    floatx4 acc[8][5];
    floatx4 zero = {0.f, 0.f, 0.f, 0.f};
#pragma unroll
    for (int i = 0; i < 8; i++)
#pragma unroll
        for (int j = 0; j < 5; j++) acc[i][j] = zero;

#define BAR() asm volatile("s_barrier" ::: "memory")
#define READB(sw) do { \
    _Pragma("unroll") for (int j_ = 0; j_ < 5; j_++) \
        bfr[j_] = *(const short8*)(Bp + bOff[j_] + (sw)); } while (0)
#define READA(h, sw) do { \
    _Pragma("unroll") for (int i_ = 0; i_ < 4; i_++) \
        af[i_] = *(const short8*)(Ap + aOff[(h) * 4 + i_] + (sw)); } while (0)
#define MM(h) do { \
    __builtin_amdgcn_s_setprio(1); \
    _Pragma("unroll") for (int i_ = 0; i_ < 4; i_++) \
    _Pragma("unroll") for (int j_ = 0; j_ < 5; j_++) \
        acc[(h) * 4 + i_][j_] = __builtin_amdgcn_mfma_f32_16x16x32_bf16( \
            __builtin_bit_cast(bf16x8, af[i_]), __builtin_bit_cast(bf16x8, bfr[j_]), \
            acc[(h) * 4 + i_][j_], 0, 0, 0); \
    __builtin_amdgcn_s_setprio(0); } while (0)
#define GA(q) gl2lds16(X + aF[q] + so, Ao + (q) * 4096 + wv * 512)
#define GB(q) gl2lds16(Wp + bF[q] + wo, Bo + (q) * 4096 + wv * 512)
#define ADV() do { ciN += 64; if (ciN == Cin) { ciN = 0; ++kkN; \
        tapOffN = ((kkN / 3) * 66 + (kkN % 3) - 67) * Cin; wbN += 640 * Cin; } } while (0)

    // flat K bookkeeping: (kkN, ciN) = coordinates of the NEXT tile to stage
    int kkN = 0, ciN = 0, tapOffN = -67 * Cin, wbN = 0;   // tap 0: dh=-1,dw=-1
    {   // prologue: stage tile 0 fully into buf 0
        const int so = tapOffN + ciN, wo = wbN + ciN;
        bf16* Ao = Alds; bf16* Bo = Blds;
        GA(0); GA(1); GA(2); GA(3);
        GB(0); GB(1); GB(2); GB(3); GB(4);
    }
    ADV();
    const int NT = 9 * (Cin >> 6);
    int p = 0;
    for (int t = 0; t < NT - 1; ++t, p ^= 1) {
        const bf16* Ap = Alds + p * 16384;
        const bf16* Bp = Blds + p * 20480;
        bf16* Ao = Alds + (p ^ 1) * 16384;
        bf16* Bo = Blds + (p ^ 1) * 20480;
        const int so = tapOffN + ciN, wo = wbN + ciN;
        short8 af[4], bfr[5];
        // 6-deep prefetch: issue 6 of tile t+1's loads, counted wait for tile t
        // (6 newer stay outstanding across the barrier -- T4, never drain)
        GA(0); GA(1); GA(2); GB(0); GB(1); GB(2);
        asm volatile("s_waitcnt vmcnt(6)" ::: "memory");
        BAR();
        // K-tile body: no intra-tile barriers; remaining 3 stages interleaved
        READB(sw0); READA(0, sw0);
        MM(0);
        READA(1, sw0);
        GA(3);
        MM(1);
        READB(sw1); READA(0, sw1);
        GB(3); GB(4);
        MM(0);
        READA(1, sw1);
        MM(1);
        BAR();   // reads of buf p complete -> iteration t+1 may re-stage p
        ADV();
    }
    {   // last tile: nothing newer outstanding -> one-time full drain
        const bf16* Ap = Alds + p * 16384;
        const bf16* Bp = Blds + p * 20480;
        short8 af[4], bfr[5];
        asm volatile("s_waitcnt vmcnt(0)" ::: "memory");
        BAR();
        READB(sw0); READA(0, sw0); MM(0);
        READA(1, sw0); MM(1);
        READB(sw1); READA(0, sw1); MM(0);
        READA(1, sw1); MM(1);
    }
#undef BAR
#undef READB
#undef READA
#undef MM
#undef GA
#undef GB
#undef ADV

    // epilogue: D[row=quad*4+r, col=lane&15] (verified m89/m91 layout)
    int ncol[5]; float sj[5], bj[5]; bool nval[5];
#pragma unroll
    for (int j = 0; j < 5; j++) {
        ncol[j] = n0 + wvN * 80 + j * 16 + r16;
        nval[j] = ncol[j] < 576;
        sj[j] = nval[j] ? inv[ncol[j]] : 0.f;
        bj[j] = nval[j] ? beta[ncol[j]] : 0.f;
    }
    if (w2 != nullptr) {
        // fused o2: partial dot over this block's cols, reduce over the 16-lane
        // col group (shfl widths 1..8 stay within the quad's 16 lanes), one
        // atomicAdd per row per (wave, quad) leader. smap pre-init to b2.
        float wj[5];
#pragma unroll
        for (int j = 0; j < 5; j++) wj[j] = nval[j] ? w2[ncol[j]] : 0.f;
#pragma unroll
        for (int i = 0; i < 8; i++) {
#pragma unroll
            for (int r = 0; r < 4; r++) {
                float ps = 0.f;
#pragma unroll
                for (int j = 0; j < 5; j++)
                    ps += (acc[i][j][r] * sj[j] + bj[j]) * wj[j];
#pragma unroll
                for (int off = 1; off < 16; off <<= 1) ps += __shfl_xor(ps, off, 64);
                if (r16 == 0)
                    atomicAdd(&smap[m0 + wvM * 128 + i * 16 + quad * 4 + r], ps);
            }
        }
    } else {
#pragma unroll
        for (int i = 0; i < 8; i++) {
#pragma unroll
            for (int r = 0; r < 4; r++) {
                int row = m0 + wvM * 128 + i * 16 + quad * 4 + r;
                int didx;
                if (dstPadded) {
                    int bb = row >> 12, hh = (row >> 6) & 63, ww = row & 63;
                    didx = (bb * 4356 + (hh + 1) * 66 + (ww + 1)) * dstC + chanOff;
                } else {
                    didx = row * dstC + chanOff;
                }
#pragma unroll
                for (int j = 0; j < 5; j++)
                    if (nval[j]) dst[didx + ncol[j]] = __float2bfloat16(acc[i][j][r] * sj[j] + bj[j]);
            }
        }
    }
}

// ---------------- tail: x8 bilinear upsample ----------------
__global__ void upsample_k(const float* __restrict__ smap, void* __restrict__ out,
                           const int* __restrict__ flag) {
    int idx = blockIdx.x * 256 + threadIdx.x;   // 8*512*512 exact
    int b = idx >> 18;
    int ho = (idx >> 9) & 511;
    int wo = idx & 511;
    const float sc = 63.f / 511.f;              // align_corners=True
    float ys = ho * sc, xs = wo * sc;
    int y0 = (int)ys; float ty = ys - y0; int y1 = min(y0 + 1, 63);
    int x0 = (int)xs; float tx = xs - x0; int x1 = min(x0 + 1, 63);
    const float* sp = smap + (b << 12);
    float r0 = sp[y0 * 64 + x0] * (1.f - tx) + sp[y0 * 64 + x1] * tx;
    float r1 = sp[y1 * 64 + x0] * (1.f - tx) + sp[y1 * 64 + x1] * tx;
    float val = r0 * (1.f - ty) + r1 * ty;
    if (*flag) ((float*)out)[idx] = val;
    else       ((bf16*)out)[idx] = __float2bfloat16(val);
}

// ---------------- launch ----------------
extern "C" void kernel_launch(void* const* d_in, const int* in_sizes, int n_in,
                              void* d_out, int out_size, void* d_ws, size_t ws_size,
                              hipStream_t stream) {
    const void* coarse = d_in[0];
    const void* x22    = d_in[1];
    const void* x31    = d_in[2];
    const void* rawx   = d_in[3];
    // d_in[4]=w_pred, d_in[5]=b_pred : dead code in reference
    const void* dec_w = d_in[6];
    const void *dec_g = d_in[7], *dec_b = d_in[8], *dec_m = d_in[9], *dec_v = d_in[10];
    const void* cc_w = d_in[11];
    const void *cc_g = d_in[12], *cc_b = d_in[13], *cc_m = d_in[14], *cc_v = d_in[15];
    const void* o1_w = d_in[16];
    const void *o1_g = d_in[17], *o1_b = d_in[18], *o1_m = d_in[19], *o1_v = d_in[20];
    const void* o2_w = d_in[21];
    const void* o2_b = d_in[22];

    // adaptive chunk ladder (weights: 640 output rows; cc K-pad 1632->1664)
    const size_t wcc_sz  = (size_t)9 * 640 * 1664 * 2;
    const size_t wsm_sz  = (size_t)9 * 640 * 576 * 2;
    const size_t tail_sz = 16384 + 131072 + 256;
    int G = 8; int sepW = 1;
    for (;;) {
        size_t acts = (size_t)G * 4356 * (576 + 1664) * 2;
        if (acts + wcc_sz + 2 * wsm_sz + tail_sz <= ws_size) { sepW = 1; break; }
        if (acts + wcc_sz + tail_sz <= ws_size)              { sepW = 0; break; }
        if (G == 1) { sepW = 0; break; }
        G >>= 1;
    }
    size_t xa_sz = (size_t)G * 4356 * 576 * 2;
    size_t xb_sz = (size_t)G * 4356 * 1664 * 2;

    char* ws = (char*)d_ws;
    bf16* Xa   = (bf16*)(ws);
    bf16* Xb   = (bf16*)(ws + xa_sz);
    bf16* Wcc  = (bf16*)(ws + xa_sz + xb_sz);
    bf16* Wdec = sepW ? (bf16*)(ws + xa_sz + xb_sz + wcc_sz) : Wcc;
    bf16* Wo1  = sepW ? (bf16*)(ws + xa_sz + xb_sz + wcc_sz + wsm_sz) : Wcc;
    size_t wtot = wcc_sz + (sepW ? 2 * wsm_sz : 0);
    float* sb  = (float*)(ws + xa_sz + xb_sz + wtot);
    float* invDec = sb,        *betaDec = sb + 576;
    float* invCc  = sb + 1152, *betaCc  = sb + 1728;
    float* invO1  = sb + 2304, *betaO1  = sb + 2880;
    float* w2f    = sb + 3456;   // 576 floats (sb region = 16384 B = 4096 floats)
    float* smap = (float*)(ws + xa_sz + xb_sz + wtot + 16384);
    int* flag   = (int*)(ws + xa_sz + xb_sz + wtot + 16384 + 131072);

    detect_k<<<1, 64, 0, stream>>>(coarse, flag);
    scale_beta_k<<<3, 256, 0, stream>>>(dec_g, dec_b, dec_m, dec_v, flag, invDec, betaDec);
    scale_beta_k<<<3, 256, 0, stream>>>(cc_g, cc_b, cc_m, cc_v, flag, invCc, betaCc);
    scale_beta_k<<<3, 256, 0, stream>>>(o1_g, o1_b, o1_m, o1_v, flag, invO1, betaO1);
    o2w_k<<<128, 256, 0, stream>>>(o2_w, o2_b, flag, w2f, smap, 32768);
    if (sepW) {
        fold_w_k<<<dim3(3, 640, 9), 256, 0, stream>>>(dec_w, Wdec, flag, 576, 576, 1);
        fold_w_k<<<dim3(7, 640, 9), 256, 0, stream>>>(cc_w, Wcc, flag, 1632, 1664, 0);
        fold_w_k<<<dim3(3, 640, 9), 256, 0, stream>>>(o1_w, Wo1, flag, 576, 576, 0);
    }

    const int nchunk = 8 / G;
    const int mt = G * 16;                 // 256-row M-tiles per chunk
    for (int q = 0; q < nchunk; q++) {
        const int b0 = q * G;
        zero_border_k<<<dim3(260, G), 256, 0, stream>>>(Xa, 576);
        zero_border_k<<<dim3(260, G), 256, 0, stream>>>(Xb, 1664);
        zero_chanpad_k<<<(G * 4356 * 4 + 255) / 256, 256, 0, stream>>>(Xb, G * 4356 * 4);
        nchw_to_pnhwc_k<<<dim3(12, 64, G), 256, 0, stream>>>(coarse, Xa, flag, 384, 576, 0, b0);
        raw_patches_k<<<dim3(64, 3, G), 256, 0, stream>>>(rawx, Xa, flag, b0);
        nchw_to_pnhwc_k<<<dim3(24, 64, G), 256, 0, stream>>>(x22, Xb, flag, 768, 1664, 0, b0);
        nchw_to_pnhwc_k<<<dim3(9, 64, G), 256, 0, stream>>>(x31, Xb, flag, 288, 1664, 1344, b0);
        if (!sepW) fold_w_k<<<dim3(3, 640, 9), 256, 0, stream>>>(dec_w, Wdec, flag, 576, 576, 1);
        conv3x3_mfma<<<dim3(mt * 2), 512, 0, stream>>>(Xa, Wdec, invDec, betaDec, Xb, 576, 1664, 768, 1, mt, nullptr, nullptr);
        if (!sepW) fold_w_k<<<dim3(7, 640, 9), 256, 0, stream>>>(cc_w, Wcc, flag, 1632, 1664, 0);
        conv3x3_mfma<<<dim3(mt * 2), 512, 0, stream>>>(Xb, Wcc, invCc, betaCc, Xa, 1664, 576, 0, 1, mt, nullptr, nullptr);
        if (!sepW) fold_w_k<<<dim3(3, 640, 9), 256, 0, stream>>>(o1_w, Wo1, flag, 576, 576, 0);
        conv3x3_mfma<<<dim3(mt * 2), 512, 0, stream>>>(Xa, Wo1, invO1, betaO1, nullptr, 576, 576, 0, 0, mt,
                                                       w2f, smap + (size_t)q * G * 4096);
    }
    upsample_k<<<8192, 256, 0, stream>>>(smap, d_out, flag);
}

// Round 8
// 1263.661 us; speedup vs baseline: 1.1873x; 1.1392x over previous
//
#include <hip/hip_runtime.h>
#include <hip/hip_bf16.h>
#include <stdint.h>

typedef __attribute__((ext_vector_type(8))) __bf16 bf16x8;
typedef __attribute__((ext_vector_type(8))) short short8;
typedef __attribute__((ext_vector_type(4))) float floatx4;
using bf16 = __hip_bfloat16;

#define DEVINL __device__ __forceinline__

typedef __attribute__((address_space(1))) const void gconst_void;
typedef __attribute__((address_space(3))) void lds_void;

DEVINL void gl2lds16(const void* g, void* l) {
    __builtin_amdgcn_global_load_lds((gconst_void*)g, (lds_void*)l, 16, 0, 0);
}

DEVINL unsigned short f2us(float x) {
    bf16 h = __float2bfloat16(x);
    return __builtin_bit_cast(unsigned short, h);
}
// flag==1: inputs are f32; flag==0: inputs are bf16
DEVINL float ld_in(const void* p, int f, size_t i) {
    return f ? ((const float*)p)[i] : __bfloat162float(((const bf16*)p)[i]);
}

// ---------------- dtype probe (confirmed: inputs are f32; keep hedge) ----------------
__global__ void detect_k(const void* x, int* flag) {
    if (threadIdx.x == 0) {
        const float* xf = (const float*)x;
        int good = 0;
        for (int i = 0; i < 64; i++) {
            float a = fabsf(xf[i]);
            if (a > 1e-8f && a < 100.f) good++;
        }
        *flag = (good >= 48) ? 1 : 0;
    }
}

// ---------------- prep kernels ----------------

__global__ void zero_border_k(bf16* buf, int C) {
    int cell = blockIdx.x;   // 0..259
    int b = blockIdx.y;
    int hp, wp;
    if (cell < 66)       { hp = 0;          wp = cell; }
    else if (cell < 132) { hp = 65;         wp = cell - 66; }
    else if (cell < 196) { hp = cell - 131; wp = 0; }
    else                 { hp = cell - 195; wp = 65; }
    unsigned short* p = (unsigned short*)buf + (size_t)(b * 4356 + hp * 66 + wp) * C;
    for (int c = threadIdx.x; c < C; c += 256) p[c] = 0;
}

// zero pad channels 1632..1663 of Xb for every cell (keeps MFMA inputs clean; weights there are 0)
__global__ void zero_chanpad_k(bf16* Xb, int n) {   // n = G*4356*4
    int idx = blockIdx.x * 256 + threadIdx.x;
    if (idx >= n) return;
    int cell = idx >> 2, sub = idx & 3;
    uint4 z; z.x = 0; z.y = 0; z.z = 0; z.w = 0;
    *(uint4*)((unsigned short*)Xb + (size_t)cell * 1664 + 1632 + sub * 8) = z;
}

__global__ void nchw_to_pnhwc_k(const void* __restrict__ src, bf16* __restrict__ dst,
                                const int* __restrict__ flag,
                                int Csrc, int dstC, int chanOff, int b0) {
    __shared__ unsigned short t[32][72];
    int c0 = blockIdx.x * 32, h = blockIdx.y, bz = blockIdx.z;
    int tid = threadIdx.x;
    {
        int c = tid >> 3, w8 = (tid & 7) * 8;
        size_t base = (((size_t)((b0 + bz) * Csrc + c0 + c)) * 64 + h) * 64 + w8;
        unsigned short* tp = &t[c][w8];
        if (*flag) {
            const float* sf = (const float*)src;
            float4 v0 = *(const float4*)(sf + base);
            float4 v1 = *(const float4*)(sf + base + 4);
            tp[0] = f2us(v0.x); tp[1] = f2us(v0.y); tp[2] = f2us(v0.z); tp[3] = f2us(v0.w);
            tp[4] = f2us(v1.x); tp[5] = f2us(v1.y); tp[6] = f2us(v1.z); tp[7] = f2us(v1.w);
        } else {
            uint4 v = *(const uint4*)((const unsigned short*)src + base);
            *(uint4*)tp = v;
        }
    }
    __syncthreads();
    {
        int w = tid >> 2, cq = (tid & 3) * 8;
        uint32_t p0 = t[cq + 0][w] | ((uint32_t)t[cq + 1][w] << 16);
        uint32_t p1 = t[cq + 2][w] | ((uint32_t)t[cq + 3][w] << 16);
        uint32_t p2 = t[cq + 4][w] | ((uint32_t)t[cq + 5][w] << 16);
        uint32_t p3 = t[cq + 6][w] | ((uint32_t)t[cq + 7][w] << 16);
        uint4 o; o.x = p0; o.y = p1; o.z = p2; o.w = p3;
        size_t off = ((size_t)(bz * 4356 + (h + 1) * 66 + (w + 1))) * dstC + chanOff + c0 + cq;
        *(uint4*)((unsigned short*)dst + off) = o;
    }
}

__global__ void raw_patches_k(const void* __restrict__ raw, bf16* __restrict__ Xa,
                              const int* __restrict__ flag, int b0) {
    __shared__ unsigned short t[8][520];
    int h = blockIdx.x, craw = blockIdx.y, bz = blockIdx.z;
    int tid = threadIdx.x;
    int f = *flag;
#pragma unroll
    for (int k = 0; k < 2; k++) {
        int s = tid + k * 256;
        int gy = s >> 6, seg = s & 63;
        size_t base = (((size_t)((b0 + bz) * 3 + craw) * 512) + gy * 64 + h) * 512 + seg * 8;
        unsigned short* tp = &t[gy][seg * 8];
        if (f) {
            const float* rf = (const float*)raw;
            float4 v0 = *(const float4*)(rf + base);
            float4 v1 = *(const float4*)(rf + base + 4);
            tp[0] = f2us(v0.x); tp[1] = f2us(v0.y); tp[2] = f2us(v0.z); tp[3] = f2us(v0.w);
            tp[4] = f2us(v1.x); tp[5] = f2us(v1.y); tp[6] = f2us(v1.z); tp[7] = f2us(v1.w);
        } else {
            uint4 v = *(const uint4*)((const unsigned short*)raw + base);
            *(uint4*)tp = v;
        }
    }
    __syncthreads();
#pragma unroll
    for (int k = 0; k < 2; k++) {
        int s = tid + k * 256;
        int w = s >> 3, gq = s & 7;
        uint32_t p0 = t[gq][0 * 64 + w] | ((uint32_t)t[gq][1 * 64 + w] << 16);
        uint32_t p1 = t[gq][2 * 64 + w] | ((uint32_t)t[gq][3 * 64 + w] << 16);
        uint32_t p2 = t[gq][4 * 64 + w] | ((uint32_t)t[gq][5 * 64 + w] << 16);
        uint32_t p3 = t[gq][6 * 64 + w] | ((uint32_t)t[gq][7 * 64 + w] << 16);
        uint4 o; o.x = p0; o.y = p1; o.z = p2; o.w = p3;
        size_t off = ((size_t)(bz * 4356 + (h + 1) * 66 + (w + 1))) * 576 + 384 + craw * 64 + gq * 8;
        *(uint4*)((unsigned short*)Xa + off) = o;
    }
}

// srcC = real input channels of the torch weight; dstC = padded K-stride of folded buffer.
// Output rows padded to 640 (rows 576..639 zero) -> 2 exact BN=320 tiles.
__global__ void fold_w_k(const void* __restrict__ W, bf16* __restrict__ dst,
                         const int* __restrict__ flag, int srcC, int dstC, int remap) {
    int ci = blockIdx.x * 256 + threadIdx.x;
    if (ci >= dstC) return;
    int co = blockIdx.y;  // 0..639
    int kk = blockIdx.z;  // 0..8
    unsigned short out = 0;
    if (co < 576 && ci < srcC) {
        int oc = ci;
        if (remap && ci >= 384) {
            int tt = ci - 384;
            int craw = tt >> 6, gy = (tt >> 3) & 7, gx = tt & 7;
            oc = 384 + gy * 24 + gx * 3 + craw;
        }
        size_t sidx = ((size_t)co * srcC + oc) * 9 + kk;
        out = (*flag) ? f2us(((const float*)W)[sidx]) : ((const unsigned short*)W)[sidx];
    }
    ((unsigned short*)dst)[((size_t)kk * 640 + co) * dstC + ci] = out;
}

__global__ void scale_beta_k(const void* g, const void* b, const void* m, const void* v,
                             const int* __restrict__ flag, float* inv_out, float* beta_out) {
    int i = blockIdx.x * 256 + threadIdx.x;
    int f = *flag;
    if (i < 576) {
        float inv = ld_in(g, f, i) / sqrtf(ld_in(v, f, i) + 1e-5f);
        inv_out[i] = inv;
        beta_out[i] = ld_in(b, f, i) - ld_in(m, f, i) * inv;
    }
}

// o2 prep: w2f[0..575] = o2 weights as f32; smap[0..npix-1] = o2 bias (fused o2
// partial-dot results are atomically accumulated on top by the o1 conv epilogue)
__global__ void o2w_k(const void* __restrict__ w, const void* __restrict__ bias,
                      const int* __restrict__ flag, float* __restrict__ w2f,
                      float* __restrict__ smap, int npix) {
    int i = blockIdx.x * 256 + threadIdx.x;
    int f = *flag;
    if (i < 576) w2f[i] = ld_in(w, f, i);
    float b2 = ld_in(bias, f, 0);
    if (i < npix) smap[i] = b2;
}

// ---------------- 3x3 conv, implicit GEMM, 2-barrier double-buffer pipeline ----------------
// BM=256 BN=320 BK=64, 512 thr / 8 waves (2M x 4N, wave tile 128x80, acc 8x5).
// EXACT r5 schedule (proven 555us cc / MfmaUtil 51%): 3 stage loads pre-issued,
// counted vmcnt(3) (never drains in steady state), remaining 6 stages
// interleaved BETWEEN the MFMA clusters, 2 barriers/K-tile, no intra-tile
// barriers. r7's 6-deep pre-issue REGRESSED to 40% (concentrating 48KB of
// LDS-DMA writes at body start collides with the body-start ds_read burst on
// the single LDS pipe) -- stage-issue PLACEMENT is a scheduling resource here,
// not just a latency knob. Keep the r7 fused-o2 epilogue (w2 != nullptr):
// per-block partial dot (acc*inv+beta).w2, 16-lane butterfly reduce, atomicAdd
// into smap (pre-init to b2) -- kills the o2_dot dispatch and o1's dst write.
// T2 XOR swizzle both-sides (0 conflicts, r1-r7). T5 setprio. T1 XCD swizzle.
__global__ __launch_bounds__(512, 2)
void conv3x3_mfma(const bf16* __restrict__ X, const bf16* __restrict__ Wp,
                  const float* __restrict__ inv, const float* __restrict__ beta,
                  bf16* __restrict__ dst, int Cin, int dstC, int chanOff, int dstPadded,
                  int mtiles, const float* __restrict__ w2, float* __restrict__ smap) {
    __shared__ __align__(16) bf16 Alds[2 * 16384];   // 2 x 32 KB : [256 rows][64]
    __shared__ __align__(16) bf16 Blds[2 * 20480];   // 2 x 40 KB : [320 rows][64]
    const int tid = threadIdx.x;
    const int wv = tid >> 6;
    const int lane = tid & 63;
    const int quad = lane >> 4;
    const int r16 = lane & 15;

    // T1: XCD-contiguous remap (nwg = 32*G, always % 8 == 0)
    const int nwg = gridDim.x;
    const int wg = ((int)blockIdx.x & 7) * (nwg >> 3) + ((int)blockIdx.x >> 3);
    const int m0 = (wg % mtiles) * 256;
    const int n0 = (wg / mtiles) * 320;

    // staging: each 64-row chunk = 8 KB = one gl2lds across 512 threads
    const int rl = tid >> 3;                          // 0..63 (row within chunk)
    const int cg = ((tid & 7) ^ (rl & 7)) * 8;        // inverse-swizzled source chunk (halfwords)
    int aF[4], bF[5];
#pragma unroll
    for (int q = 0; q < 4; q++) {
        int r = m0 + q * 64 + rl;
        int bb = r >> 12, hh = (r >> 6) & 63;
        aF[q] = (bb * 4356 + (hh + 1) * 66 + (rl + 1)) * Cin + cg;
    }
#pragma unroll
    for (int q = 0; q < 5; q++) bF[q] = (n0 + q * 64 + rl) * Cin + cg;

    // fragment-read geometry (wave tile 128x80: 8 M-frags x 5 N-frags)
    const int wvM = wv >> 2, wvN = wv & 3;
    int aOff[8], bOff[5];
#pragma unroll
    for (int i = 0; i < 8; i++) aOff[i] = (wvM * 128 + i * 16 + r16) * 64;
#pragma unroll
    for (int j = 0; j < 5; j++) bOff[j] = (wvN * 80 + j * 16 + r16) * 64;
    const int sw0 = (quad ^ (r16 & 7)) * 8;           // swizzled chunk, kq=0
    const int sw1 = ((quad + 4) ^ (r16 & 7)) * 8;     // swizzled chunk, kq=1

    floatx4 acc[8][5];
    floatx4 zero = {0.f, 0.f, 0.f, 0.f};
#pragma unroll
    for (int i = 0; i < 8; i++)
#pragma unroll
        for (int j = 0; j < 5; j++) acc[i][j] = zero;

#define BAR() asm volatile("s_barrier" ::: "memory")
#define READB(sw) do { \
    _Pragma("unroll") for (int j_ = 0; j_ < 5; j_++) \
        bfr[j_] = *(const short8*)(Bp + bOff[j_] + (sw)); } while (0)
#define READA(h, sw) do { \
    _Pragma("unroll") for (int i_ = 0; i_ < 4; i_++) \
        af[i_] = *(const short8*)(Ap + aOff[(h) * 4 + i_] + (sw)); } while (0)
#define MM(h) do { \
    __builtin_amdgcn_s_setprio(1); \
    _Pragma("unroll") for (int i_ = 0; i_ < 4; i_++) \
    _Pragma("unroll") for (int j_ = 0; j_ < 5; j_++) \
        acc[(h) * 4 + i_][j_] = __builtin_amdgcn_mfma_f32_16x16x32_bf16( \
            __builtin_bit_cast(bf16x8, af[i_]), __builtin_bit_cast(bf16x8, bfr[j_]), \
            acc[(h) * 4 + i_][j_], 0, 0, 0); \
    __builtin_amdgcn_s_setprio(0); } while (0)
#define GA(q) gl2lds16(X + aF[q] + so, Ao + (q) * 4096 + wv * 512)
#define GB(q) gl2lds16(Wp + bF[q] + wo, Bo + (q) * 4096 + wv * 512)
#define ADV() do { ciN += 64; if (ciN == Cin) { ciN = 0; ++kkN; \
        tapOffN = ((kkN / 3) * 66 + (kkN % 3) - 67) * Cin; wbN += 640 * Cin; } } while (0)

    // flat K bookkeeping: (kkN, ciN) = coordinates of the NEXT tile to stage
    int kkN = 0, ciN = 0, tapOffN = -67 * Cin, wbN = 0;   // tap 0: dh=-1,dw=-1
    {   // prologue: stage tile 0 fully into buf 0
        const int so = tapOffN + ciN, wo = wbN + ciN;
        bf16* Ao = Alds; bf16* Bo = Blds;
        GA(0); GA(1); GA(2); GA(3);
        GB(0); GB(1); GB(2); GB(3); GB(4);
    }
    ADV();
    const int NT = 9 * (Cin >> 6);
    int p = 0;
    for (int t = 0; t < NT - 1; ++t, p ^= 1) {
        const bf16* Ap = Alds + p * 16384;
        const bf16* Bp = Blds + p * 20480;
        bf16* Ao = Alds + (p ^ 1) * 16384;
        bf16* Bo = Blds + (p ^ 1) * 20480;
        const int so = tapOffN + ciN, wo = wbN + ciN;
        short8 af[4], bfr[5];
        // r5 schedule: 3 pre-issues, counted wait (3 newest stay in flight
        // across the barrier), validity barrier
        GA(0); GA(1); GA(2);
        asm volatile("s_waitcnt vmcnt(3)" ::: "memory");
        BAR();
        // body: no intra-tile barriers; remaining 6 stages interleaved between
        // MFMA clusters (spreads LDS-DMA writes under the MFMA windows)
        READB(sw0); READA(0, sw0);
        MM(0);
        READA(1, sw0);
        GA(3); GB(0); GB(1);
        MM(1);
        READB(sw1); READA(0, sw1);
        GB(2); GB(3); GB(4);
        MM(0);
        READA(1, sw1);
        MM(1);
        BAR();   // reads of buf p complete -> iteration t+1 may re-stage p
        ADV();
    }
    {   // last tile: nothing newer outstanding -> one-time full drain
        const bf16* Ap = Alds + p * 16384;
        const bf16* Bp = Blds + p * 20480;
        short8 af[4], bfr[5];
        asm volatile("s_waitcnt vmcnt(0)" ::: "memory");
        BAR();
        READB(sw0); READA(0, sw0); MM(0);
        READA(1, sw0); MM(1);
        READB(sw1); READA(0, sw1); MM(0);
        READA(1, sw1); MM(1);
    }
#undef BAR
#undef READB
#undef READA
#undef MM
#undef GA
#undef GB
#undef ADV

    // epilogue: D[row=quad*4+r, col=lane&15] (verified m89/m91 layout)
    int ncol[5]; float sj[5], bj[5]; bool nval[5];
#pragma unroll
    for (int j = 0; j < 5; j++) {
        ncol[j] = n0 + wvN * 80 + j * 16 + r16;
        nval[j] = ncol[j] < 576;
        sj[j] = nval[j] ? inv[ncol[j]] : 0.f;
        bj[j] = nval[j] ? beta[ncol[j]] : 0.f;
    }
    if (w2 != nullptr) {
        // fused o2: partial dot over this block's cols, butterfly-reduce over
        // the 16-lane col group, one atomicAdd per row per (wave, quad) leader.
        float wj[5];
#pragma unroll
        for (int j = 0; j < 5; j++) wj[j] = nval[j] ? w2[ncol[j]] : 0.f;
#pragma unroll
        for (int i = 0; i < 8; i++) {
#pragma unroll
            for (int r = 0; r < 4; r++) {
                float ps = 0.f;
#pragma unroll
                for (int j = 0; j < 5; j++)
                    ps += (acc[i][j][r] * sj[j] + bj[j]) * wj[j];
#pragma unroll
                for (int off = 1; off < 16; off <<= 1) ps += __shfl_xor(ps, off, 64);
                if (r16 == 0)
                    atomicAdd(&smap[m0 + wvM * 128 + i * 16 + quad * 4 + r], ps);
            }
        }
    } else {
#pragma unroll
        for (int i = 0; i < 8; i++) {
#pragma unroll
            for (int r = 0; r < 4; r++) {
                int row = m0 + wvM * 128 + i * 16 + quad * 4 + r;
                int didx;
                if (dstPadded) {
                    int bb = row >> 12, hh = (row >> 6) & 63, ww = row & 63;
                    didx = (bb * 4356 + (hh + 1) * 66 + (ww + 1)) * dstC + chanOff;
                } else {
                    didx = row * dstC + chanOff;
                }
#pragma unroll
                for (int j = 0; j < 5; j++)
                    if (nval[j]) dst[didx + ncol[j]] = __float2bfloat16(acc[i][j][r] * sj[j] + bj[j]);
            }
        }
    }
}

// ---------------- tail: x8 bilinear upsample ----------------
__global__ void upsample_k(const float* __restrict__ smap, void* __restrict__ out,
                           const int* __restrict__ flag) {
    int idx = blockIdx.x * 256 + threadIdx.x;   // 8*512*512 exact
    int b = idx >> 18;
    int ho = (idx >> 9) & 511;
    int wo = idx & 511;
    const float sc = 63.f / 511.f;              // align_corners=True
    float ys = ho * sc, xs = wo * sc;
    int y0 = (int)ys; float ty = ys - y0; int y1 = min(y0 + 1, 63);
    int x0 = (int)xs; float tx = xs - x0; int x1 = min(x0 + 1, 63);
    const float* sp = smap + (b << 12);
    float r0 = sp[y0 * 64 + x0] * (1.f - tx) + sp[y0 * 64 + x1] * tx;
    float r1 = sp[y1 * 64 + x0] * (1.f - tx) + sp[y1 * 64 + x1] * tx;
    float val = r0 * (1.f - ty) + r1 * ty;
    if (*flag) ((float*)out)[idx] = val;
    else       ((bf16*)out)[idx] = __float2bfloat16(val);
}

// ---------------- launch ----------------
extern "C" void kernel_launch(void* const* d_in, const int* in_sizes, int n_in,
                              void* d_out, int out_size, void* d_ws, size_t ws_size,
                              hipStream_t stream) {
    const void* coarse = d_in[0];
    const void* x22    = d_in[1];
    const void* x31    = d_in[2];
    const void* rawx   = d_in[3];
    // d_in[4]=w_pred, d_in[5]=b_pred : dead code in reference
    const void* dec_w = d_in[6];
    const void *dec_g = d_in[7], *dec_b = d_in[8], *dec_m = d_in[9], *dec_v = d_in[10];
    const void* cc_w = d_in[11];
    const void *cc_g = d_in[12], *cc_b = d_in[13], *cc_m = d_in[14], *cc_v = d_in[15];
    const void* o1_w = d_in[16];
    const void *o1_g = d_in[17], *o1_b = d_in[18], *o1_m = d_in[19], *o1_v = d_in[20];
    const void* o2_w = d_in[21];
    const void* o2_b = d_in[22];

    // adaptive chunk ladder (weights: 640 output rows; cc K-pad 1632->1664)
    const size_t wcc_sz  = (size_t)9 * 640 * 1664 * 2;
    const size_t wsm_sz  = (size_t)9 * 640 * 576 * 2;
    const size_t tail_sz = 16384 + 131072 + 256;
    int G = 8; int sepW = 1;
    for (;;) {
        size_t acts = (size_t)G * 4356 * (576 + 1664) * 2;
        if (acts + wcc_sz + 2 * wsm_sz + tail_sz <= ws_size) { sepW = 1; break; }
        if (acts + wcc_sz + tail_sz <= ws_size)              { sepW = 0; break; }
        if (G == 1) { sepW = 0; break; }
        G >>= 1;
    }
    size_t xa_sz = (size_t)G * 4356 * 576 * 2;
    size_t xb_sz = (size_t)G * 4356 * 1664 * 2;

    char* ws = (char*)d_ws;
    bf16* Xa   = (bf16*)(ws);
    bf16* Xb   = (bf16*)(ws + xa_sz);
    bf16* Wcc  = (bf16*)(ws + xa_sz + xb_sz);
    bf16* Wdec = sepW ? (bf16*)(ws + xa_sz + xb_sz + wcc_sz) : Wcc;
    bf16* Wo1  = sepW ? (bf16*)(ws + xa_sz + xb_sz + wcc_sz + wsm_sz) : Wcc;
    size_t wtot = wcc_sz + (sepW ? 2 * wsm_sz : 0);
    float* sb  = (float*)(ws + xa_sz + xb_sz + wtot);
    float* invDec = sb,        *betaDec = sb + 576;
    float* invCc  = sb + 1152, *betaCc  = sb + 1728;
    float* invO1  = sb + 2304, *betaO1  = sb + 2880;
    float* w2f    = sb + 3456;   // 576 floats (sb region = 16384 B = 4096 floats)
    float* smap = (float*)(ws + xa_sz + xb_sz + wtot + 16384);
    int* flag   = (int*)(ws + xa_sz + xb_sz + wtot + 16384 + 131072);

    detect_k<<<1, 64, 0, stream>>>(coarse, flag);
    scale_beta_k<<<3, 256, 0, stream>>>(dec_g, dec_b, dec_m, dec_v, flag, invDec, betaDec);
    scale_beta_k<<<3, 256, 0, stream>>>(cc_g, cc_b, cc_m, cc_v, flag, invCc, betaCc);
    scale_beta_k<<<3, 256, 0, stream>>>(o1_g, o1_b, o1_m, o1_v, flag, invO1, betaO1);
    o2w_k<<<128, 256, 0, stream>>>(o2_w, o2_b, flag, w2f, smap, 32768);
    if (sepW) {
        fold_w_k<<<dim3(3, 640, 9), 256, 0, stream>>>(dec_w, Wdec, flag, 576, 576, 1);
        fold_w_k<<<dim3(7, 640, 9), 256, 0, stream>>>(cc_w, Wcc, flag, 1632, 1664, 0);
        fold_w_k<<<dim3(3, 640, 9), 256, 0, stream>>>(o1_w, Wo1, flag, 576, 576, 0);
    }

    const int nchunk = 8 / G;
    const int mt = G * 16;                 // 256-row M-tiles per chunk
    for (int q = 0; q < nchunk; q++) {
        const int b0 = q * G;
        zero_border_k<<<dim3(260, G), 256, 0, stream>>>(Xa, 576);
        zero_border_k<<<dim3(260, G), 256, 0, stream>>>(Xb, 1664);
        zero_chanpad_k<<<(G * 4356 * 4 + 255) / 256, 256, 0, stream>>>(Xb, G * 4356 * 4);
        nchw_to_pnhwc_k<<<dim3(12, 64, G), 256, 0, stream>>>(coarse, Xa, flag, 384, 576, 0, b0);
        raw_patches_k<<<dim3(64, 3, G), 256, 0, stream>>>(rawx, Xa, flag, b0);
        nchw_to_pnhwc_k<<<dim3(24, 64, G), 256, 0, stream>>>(x22, Xb, flag, 768, 1664, 0, b0);
        nchw_to_pnhwc_k<<<dim3(9, 64, G), 256, 0, stream>>>(x31, Xb, flag, 288, 1664, 1344, b0);
        if (!sepW) fold_w_k<<<dim3(3, 640, 9), 256, 0, stream>>>(dec_w, Wdec, flag, 576, 576, 1);
        conv3x3_mfma<<<dim3(mt * 2), 512, 0, stream>>>(Xa, Wdec, invDec, betaDec, Xb, 576, 1664, 768, 1, mt, nullptr, nullptr);
        if (!sepW) fold_w_k<<<dim3(7, 640, 9), 256, 0, stream>>>(cc_w, Wcc, flag, 1632, 1664, 0);
        conv3x3_mfma<<<dim3(mt * 2), 512, 0, stream>>>(Xb, Wcc, invCc, betaCc, Xa, 1664, 576, 0, 1, mt, nullptr, nullptr);
        if (!sepW) fold_w_k<<<dim3(3, 640, 9), 256, 0, stream>>>(o1_w, Wo1, flag, 576, 576, 0);
        conv3x3_mfma<<<dim3(mt * 2), 512, 0, stream>>>(Xa, Wo1, invO1, betaO1, nullptr, 576, 576, 0, 0, mt,
                                                       w2f, smap + (size_t)q * G * 4096);
    }
    upsample_k<<<8192, 256, 0, stream>>>(smap, d_out, flag);
}